// Round 1
// 511.784 us; speedup vs baseline: 1.0565x; 1.0565x over previous
//
#include <hip/hip_runtime.h>
#include <math.h>

// ---------------- FDTD time-skewed tiling, register-resident fields ----------------
// 400x400 grid, 300 steps, batch 2. Tile: 40x40 interior + halo 12 -> 64x64 ext.
// Block = 512 threads = 8 waves; wave w owns ext rows [8w, 8w+8), lane = ext col.
// Fields live in registers (8 rows/lane). Column neighbors via DPP wave shifts
// (VALU pipe, not DS — ds_bpermute was the per-CU bottleneck); wave-boundary
// rows via tiny ping-pong LDS exchange; ONE barrier per step. 25 rounds x 12 steps.
#define NXg 400
#define NYg 400
#define NN (NXg * NYg)
#define SRC_I 30
#define DET_I 370
#define TILE_B 40
#define HALO 12
#define NTI 10          // tiles per dim (10*40 = 400 exact)
#define ROUNDS 25
#define RSTEPS 12
#define NB 2
#define XSLOT 576       // 9 slots * 64 lanes (slot 0 or 8 = ghost zeros)

static constexpr float DT_F     = (float)(0.5 * 25e-9 / 299792458.0);     // COURANT*DX/C0
static constexpr float PERIOD_F = (float)(1550e-9 / 299792458.0);         // WAVELENGTH/C0
static constexpr float TWOPI_F  = (float)(2.0 * 3.14159265358979323846);
static constexpr float PI_F     = (float)3.14159265358979323846;

// shared helper so the redundant "row above" Hy update compiles identically
__device__ __forceinline__ float hupd(float damp, float h, float d) {
    return damp * (h + 0.5f * d);
}

// DPP full-wave shifts (gfx9/CDNA): execute on VALU pipe, zero DS traffic.
// wave_shr:1 (0x138): dest lane n = src lane n-1  == __shfl_up(x,1,64)
// wave_shl:1 (0x130): dest lane n = src lane n+1  == __shfl_down(x,1,64)
// bound_ctrl=true: invalid lane (0 resp. 63) reads 0 — those lanes are in the
// skew-discarded ext edge, never stored, so results are bitwise-identical.
__device__ __forceinline__ float shup1(float x) {
    return __int_as_float(
        __builtin_amdgcn_update_dpp(0, __float_as_int(x), 0x138, 0xF, 0xF, true));
}
__device__ __forceinline__ float shdn1(float x) {
    return __int_as_float(
        __builtin_amdgcn_update_dpp(0, __float_as_int(x), 0x130, 0xF, 0xF, true));
}

// ---- one-time (per call) setup: zero states, build rc = COURANT/eps, damp profile ----
__global__ void fdtd_setup(const float* __restrict__ radius,
                           float* __restrict__ Ez_g, float* __restrict__ Hx_g,
                           float* __restrict__ Hy_g, float* __restrict__ rc_g,
                           float* __restrict__ px_g)
{
    int idx = blockIdx.x * blockDim.x + threadIdx.x;
    if (idx >= NN) return;
    int i = idx / NYg, j = idx % NYg;

    Ez_g[idx] = 0.f; Ez_g[idx + NN] = 0.f;
    Hx_g[idx] = 0.f; Hx_g[idx + NN] = 0.f;
    Hy_g[idx] = 0.f; Hy_g[idx + NN] = 0.f;

    float eps = 1.0f;
    int dj = j - 70;  // port columns: [70..89],[150..169],[230..249],[310..329]
    bool port = (dj >= 0) && (dj < 260) && ((dj % 80) < 20);
    if (port && (i < SRC_I || i >= DET_I)) eps = 2.8f;
    if (i >= 80 && i < 320 && j >= 80 && j < 320) {
        float x = (float)(i - 80), y = (float)(j - 80);
        bool inside = false;
        for (int a = 0; a < 64; ++a) {
            float r = radius[a];
            r = (r < 0.3f) ? 0.f : r;
            float cx = (float)(15 + 30 * (a >> 3));
            float cy = (float)(15 + 30 * (a & 7));
            float dx = x - cx, dy = y - cy;
            if (dx * dx + dy * dy <= r * r) inside = true;
        }
        eps = inside ? 1.0f : 2.8f;
    }
    rc_g[idx] = 0.5f / eps;

    if (idx < NXg) {
        double prof = 1.0;
        if (idx < 10) {
            double rmp = (10.0 - (double)idx - 0.5) / 10.0;
            prof = exp(-0.5 * rmp * rmp * rmp);
        } else if (idx >= NXg - 10) {
            double rmp = ((double)(idx - (NXg - 10)) + 0.5) / 10.0;
            prof = exp(-0.5 * rmp * rmp * rmp);
        }
        px_g[idx] = (float)prof;
    }
}

// ---- one round: load regs -> 12 local steps (regs + DPP shifts) -> store interior ----
__global__ __launch_bounds__(512)
void fdtd_round(const float* __restrict__ phase,
                float* __restrict__ Ez_g, float* __restrict__ Hx_g,
                float* __restrict__ Hy_g, const float* __restrict__ rc_g,
                const float* __restrict__ px_g, int t0)
{
    // ping-pong wave-boundary exchange buffers
    __shared__ float xEz0[2][XSLOT];   // slot w   = wave w's Ez row0; slot 8 ghost
    __shared__ float xEz7[2][XSLOT];   // slot w+1 = wave w's Ez row7; slot 0 ghost
    __shared__ float xHy7[2][XSLOT];   // slot w+1 = wave w's Hy row7 (pre-update)

    const int tid = threadIdx.x;
    const int w   = tid >> 6;
    const int lj  = tid & 63;
    const int b   = blockIdx.z;
    const int gx0 = blockIdx.x * TILE_B - HALO;
    const int gy0 = blockIdx.y * TILE_B - HALO;
    const int gj  = gy0 + lj;
    const int gib = gx0 + 8 * w;       // global row of register r=0
    const size_t bb = (size_t)b * NN;

    if (tid < 64) {
        #pragma unroll
        for (int p = 0; p < 2; ++p) {
            xEz0[p][512 + tid] = 0.f;
            xEz7[p][tid] = 0.f;
            xHy7[p][tid] = 0.f;
        }
    }

    const bool jin = (gj >= 0) && (gj < NYg);
    const float pyv = jin ? px_g[gj] : 0.f;

    float Ez[8], Hx[8], Hy[8], rc[8], dmp[8];
    #pragma unroll
    for (int r = 0; r < 8; ++r) {
        const int gi = gib + r;
        const bool in = jin && (gi >= 0) && (gi < NXg);
        if (in) {
            const size_t go = bb + (size_t)gi * NYg + gj;
            Ez[r] = Ez_g[go]; Hx[r] = Hx_g[go]; Hy[r] = Hy_g[go];
            rc[r] = rc_g[(size_t)gi * NYg + gj];
            dmp[r] = px_g[gi] * pyv;
        } else {
            Ez[r] = 0.f; Hx[r] = 0.f; Hy[r] = 0.f; rc[r] = 0.5f; dmp[r] = 0.f;
        }
    }
    float dmpA = 0.f;   // damp of the row just above this wave's rows
    { const int giA = gib - 1; if (jin && giA >= 0 && giA < NXg) dmpA = px_g[giA] * pyv; }

    const int djp = gj - 70;
    const int pport = (djp >= 0 && djp < 260 && (djp % 80) < 20) ? (djp / 80) : -1;
    const float phv = (pport >= 0) ? phase[b * 4 + pport] : 0.f;
    const bool gYlt = (gj < NYg - 1);
    const bool gYgt = (gj > 0);
    const bool hasSrc = (gib <= SRC_I) && (SRC_I < gib + 8);

    for (int s = 0; s < RSTEPS; ++s) {
        const int p = s & 1;
        // publish wave-boundary rows (pre-update values)
        xEz0[p][(w << 6) + lj] = Ez[0];
        xEz7[p][((w + 1) << 6) + lj] = Ez[7];
        xHy7[p][((w + 1) << 6) + lj] = Hy[7];
        __syncthreads();
        const float ezB  = xEz0[p][((w + 1) << 6) + lj];   // Ez of row below (wave w+1 row0)
        const float ezA7 = xEz7[p][(w << 6) + lj];         // Ez of row above (wave w-1 row7)
        const float hyA7 = xHy7[p][(w << 6) + lj];         // Hy of row above (pre-update)
        // redundant Hy update of the row above — bitwise-identical inputs/expression
        const float dexA = (gib - 1 < NXg - 1) ? (Ez[0] - ezA7) : 0.f;
        const float hyA  = hupd(dmpA, hyA7, dexA);

        // ---- H update (registers + DPP column shifts) ----
        float ezn[8];
        #pragma unroll
        for (int r = 0; r < 7; ++r) ezn[r] = Ez[r + 1];
        ezn[7] = ezB;
        #pragma unroll
        for (int r = 0; r < 8; ++r) {
            const int gi = gib + r;
            const float ezr = shdn1(Ez[r]);                 // Ez at gj+1 (VALU DPP)
            const float dey = gYlt ? (ezr - Ez[r]) : 0.f;
            const float dex = (gi < NXg - 1) ? (ezn[r] - Ez[r]) : 0.f;
            Hx[r] = hupd(dmp[r], Hx[r], -dey);
            Hy[r] = hupd(dmp[r], Hy[r], dex);
        }

        // ---- E update + soft source ----
        const float tf = (float)(t0 + s);
        float hyprev = hyA;
        #pragma unroll
        for (int r = 0; r < 8; ++r) {
            const int gi = gib + r;
            const float hxl = shup1(Hx[r]);                 // Hx at gj-1 (VALU DPP)
            const float dhyx = (gi > 0) ? (Hy[r] - hyprev) : 0.f;
            const float dhxy = gYgt ? (Hx[r] - hxl) : 0.f;
            float ez = dmp[r] * (Ez[r] + rc[r] * (dhyx - dhxy));
            if (hasSrc && (gi == SRC_I) && (pport >= 0)) {
                const float a = tf * DT_F;                  // JAX f32 op order
                ez += sinf(TWOPI_F * a / PERIOD_F + PI_F * phv);
            }
            Ez[r] = ez;
            hyprev = Hy[r];
        }
        // single barrier per step: ping-pong buffers make a 2nd barrier unnecessary
    }

    // store interior [HALO, HALO+TILE_B) — exact tiling
    if (lj >= HALO && lj < HALO + TILE_B) {
        #pragma unroll
        for (int r = 0; r < 8; ++r) {
            const int li = (w << 3) + r;
            if (li >= HALO && li < HALO + TILE_B) {
                const int gi = gx0 + li;
                const size_t go = bb + (size_t)gi * NYg + gj;
                Ez_g[go] = Ez[r];
                Hx_g[go] = Hx[r];
                Hy_g[go] = Hy[r];
            }
        }
    }
}

// ---- detector gather: out[b][p][k] = Ez[DET_I, 80*(p+1)-10+k] ----
__global__ void fdtd_gather(const float* __restrict__ Ez_g, float* __restrict__ out)
{
    int idx = threadIdx.x;
    if (idx < NB * 80) {
        int b = idx / 80, rem = idx % 80, p = rem / 20, k = rem % 20;
        int gj = (p + 1) * 80 - 10 + k;
        out[idx] = Ez_g[(size_t)b * NN + (size_t)DET_I * NYg + gj];
    }
}

extern "C" void kernel_launch(void* const* d_in, const int* in_sizes, int n_in,
                              void* d_out, int out_size, void* d_ws, size_t ws_size,
                              hipStream_t stream)
{
    const float* phase  = (const float*)d_in[0];   // (2,4) f32
    const float* radius = (const float*)d_in[1];   // (8,8) f32
    float* ws = (float*)d_ws;
    // workspace layout (floats): Ez[2*NN] | Hx[2*NN] | Hy[2*NN] | rc[NN] | px[400]
    float* Ez_g = ws;
    float* Hx_g = ws + 2 * NN;
    float* Hy_g = ws + 4 * NN;
    float* rc_g = ws + 6 * NN;
    float* px_g = ws + 7 * NN;

    fdtd_setup<<<(NN + 255) / 256, 256, 0, stream>>>(radius, Ez_g, Hx_g, Hy_g, rc_g, px_g);

    dim3 grid(NTI, NTI, NB);
    for (int r = 0; r < ROUNDS; ++r) {
        fdtd_round<<<grid, 512, 0, stream>>>(phase, Ez_g, Hx_g, Hy_g, rc_g, px_g, r * RSTEPS);
    }

    fdtd_gather<<<1, 256, 0, stream>>>(Ez_g, (float*)d_out);
}